// Round 1
// baseline (253.724 us; speedup 1.0000x reference)
//
#include <hip/hip_runtime.h>

// LIF neuron bank: B=16, N=2048, T=1000.
// Sequential scan over T per neuron; 32768 independent neurons = 512 waves.
// FP discipline: reference (numpy / XLA-CPU) does NOT contract mul+add into
// FMA. Use __fmul_rn/__fadd_rn/__fsub_rn everywhere on the trajectory path so
// we stay bit-exact (a 1-ULP divergence can flip a spike -> absmax 1.0 fail).

constexpr int B_ = 16;
constexpr int N_ = 2048;
constexpr int T_ = 1000;

__global__ __launch_bounds__(64) void lif_kernel(
    const float* __restrict__ u,          // (B, N, T)
    const float* __restrict__ theta_base, // (1, N, 1) -> N floats
    float* __restrict__ spikes,           // (B, N, T)
    float* __restrict__ vhist)            // (B, N, T)
{
    const int tid = blockIdx.x * 64 + threadIdx.x;  // = b*N + n
    const int n = tid & (N_ - 1);

    const float tb = theta_base[n];
    // c = tb * float32(1.0 - 0.995)  (the f64 expression rounds to 0.005f)
    const float c = __fmul_rn(tb, 0.005f);

    float v = 0.0f;
    float theta = tb;    // theta0 = broadcast(tb)
    float ref = 0.0f;

    const float* up = u + (size_t)tid * T_;
    float* sp = spikes + (size_t)tid * T_;
    float* vp = vhist + (size_t)tid * T_;

    // float4-aligned: tid*T_*4 bytes = tid*4000, 4000 % 16 == 0.
    float4 u4 = *reinterpret_cast<const float4*>(up);

    for (int t = 0; t < T_; t += 4) {
        float4 unext;
        if (t + 4 < T_) {
            unext = *reinterpret_cast<const float4*>(up + t + 4);
        } else {
            unext = make_float4(0.f, 0.f, 0.f, 0.f);
        }

        float uin[4] = {u4.x, u4.y, u4.z, u4.w};
        float sout[4], vout[4];

#pragma unroll
        for (int k = 0; k < 4; ++k) {
            // u_eff = u_t * (1 - (ref > 0))   (select == mul-by-0/1 up to -0)
            const float ueff = (ref > 0.0f) ? 0.0f : uin[k];
            // v = ALPHA * v + u_eff    (separate mul, add -- NO fma)
            v = __fadd_rn(__fmul_rn(0.95f, v), ueff);
            // s = (v - theta >= 0)
            const float d = __fsub_rn(v, theta);
            const bool s = (d >= 0.0f);
            // v = v - s * theta
            v = s ? __fsub_rn(v, theta) : v;
            // ref = max(ref - 1, 0); if (s) ref = 2
            ref = fmaxf(__fsub_rn(ref, 1.0f), 0.0f);
            ref = s ? 2.0f : ref;
            // theta = theta*0.995 + tb*0.005 + 0.35*s   (left-to-right adds)
            theta = __fadd_rn(__fmul_rn(theta, 0.995f), c);
            theta = s ? __fadd_rn(theta, 0.35f) : theta;

            sout[k] = s ? 1.0f : 0.0f;
            vout[k] = v;
        }

        *reinterpret_cast<float4*>(sp + t) =
            make_float4(sout[0], sout[1], sout[2], sout[3]);
        *reinterpret_cast<float4*>(vp + t) =
            make_float4(vout[0], vout[1], vout[2], vout[3]);

        u4 = unext;
    }
}

extern "C" void kernel_launch(void* const* d_in, const int* in_sizes, int n_in,
                              void* d_out, int out_size, void* d_ws, size_t ws_size,
                              hipStream_t stream) {
    const float* u = (const float*)d_in[0];           // (B,N,T)
    const float* theta_base = (const float*)d_in[1];  // (1,N,1)
    float* out = (float*)d_out;
    float* spikes = out;                                // first output
    float* vhist = out + (size_t)B_ * N_ * T_;          // second output

    const int total = B_ * N_;        // 32768 threads
    const int block = 64;
    const int grid = total / block;   // 512 blocks -> 2 per CU
    lif_kernel<<<grid, block, 0, stream>>>(u, theta_base, spikes, vhist);
}

// Round 2
// 173.706 us; speedup vs baseline: 1.4607x; 1.4607x over previous
//
#include <hip/hip_runtime.h>

// LIF neuron bank: B=16, N=2048, T=1000. One thread per (b,n) neuron;
// sequential scan over its contiguous T-row. 512 waves total (structural).
//
// R1: chunked processing (40 steps = 10 float4) with double-buffered loads.
//  - 10 back-to-back loads per chunk -> ~10 outstanding -> HBM latency /10.
//  - 10+10 back-to-back float4 stores per chunk (160B contiguous per row)
//    -> L2 write-combining sees full lines quickly (R0 had 1.77x write amp).
//  - Named A/B buffers (static indexing only -- runtime-indexed arrays
//    spill to scratch on hipcc).
//
// FP discipline: reference (numpy/XLA) does NOT contract mul+add into FMA.
// __fmul_rn/__fadd_rn/__fsub_rn keep the trajectory bit-exact (R0: absmax 0).

constexpr int B_ = 16;
constexpr int N_ = 2048;
constexpr int T_ = 1000;
constexpr int CHUNK = 40;            // steps per chunk
constexpr int NV4 = CHUNK / 4;       // 10 float4 per chunk
constexpr int NCHUNK = T_ / CHUNK;   // 25 chunks
constexpr int NPAIR = NCHUNK / 2;    // 12 pairs, 1 tail chunk

__global__ __launch_bounds__(64) void lif_kernel(
    const float* __restrict__ u,          // (B, N, T)
    const float* __restrict__ theta_base, // (1, N, 1) -> N floats
    float* __restrict__ spikes,           // (B, N, T)
    float* __restrict__ vhist)            // (B, N, T)
{
    const int tid = blockIdx.x * 64 + threadIdx.x;  // = b*N + n
    const int n = tid & (N_ - 1);

    const float tb = theta_base[n];
    const float c5 = __fmul_rn(tb, 0.005f);  // tb * (1 - 0.995) rounded

    float v = 0.0f;
    float theta = tb;
    float ref = 0.0f;

    const float* up = u + (size_t)tid * T_;
    float* sp = spikes + (size_t)tid * T_;
    float* vp = vhist + (size_t)tid * T_;

    float4 bufA[NV4], bufB[NV4];

    auto load_chunk = [&](float4 (&buf)[NV4], int t0) {
#pragma unroll
        for (int i = 0; i < NV4; ++i)
            buf[i] = *reinterpret_cast<const float4*>(up + t0 + 4 * i);
    };

    auto process = [&](const float4 (&buf)[NV4], int t0) {
        float4 s4[NV4], v4[NV4];
#pragma unroll
        for (int i = 0; i < NV4; ++i) {
            const float uin[4] = {buf[i].x, buf[i].y, buf[i].z, buf[i].w};
            float so[4], vo[4];
#pragma unroll
            for (int k = 0; k < 4; ++k) {
                // u_eff = u_t * (1 - (ref>0))
                const float ueff = (ref > 0.0f) ? 0.0f : uin[k];
                // v = 0.95*v + u_eff  (separate mul/add, no FMA)
                v = __fadd_rn(__fmul_rn(0.95f, v), ueff);
                // s = (v - theta >= 0)
                const float d = __fsub_rn(v, theta);
                const bool s = (d >= 0.0f);
                // v -= s*theta
                v = s ? __fsub_rn(v, theta) : v;
                // ref = max(ref-1, 0); if (s) ref = 2
                ref = fmaxf(__fsub_rn(ref, 1.0f), 0.0f);
                ref = s ? 2.0f : ref;
                // theta = theta*0.995 + tb*0.005 + 0.35*s
                theta = __fadd_rn(__fmul_rn(theta, 0.995f), c5);
                theta = s ? __fadd_rn(theta, 0.35f) : theta;

                so[k] = s ? 1.0f : 0.0f;
                vo[k] = v;
            }
            s4[i] = make_float4(so[0], so[1], so[2], so[3]);
            v4[i] = make_float4(vo[0], vo[1], vo[2], vo[3]);
        }
        // batched stores: 160B contiguous per row, back-to-back
#pragma unroll
        for (int i = 0; i < NV4; ++i)
            *reinterpret_cast<float4*>(sp + t0 + 4 * i) = s4[i];
#pragma unroll
        for (int i = 0; i < NV4; ++i)
            *reinterpret_cast<float4*>(vp + t0 + 4 * i) = v4[i];
    };

    // software pipeline: load chunk c+1 while computing chunk c
    load_chunk(bufA, 0);
    int t = 0;
#pragma unroll 1
    for (int c = 0; c < NPAIR; ++c) {
        load_chunk(bufB, t + CHUNK);        // chunk 2c+1
        process(bufA, t);                   // chunk 2c
        t += CHUNK;
        load_chunk(bufA, t + CHUNK);        // chunk 2c+2 (<= 24, always valid)
        process(bufB, t);                   // chunk 2c+1
        t += CHUNK;
    }
    process(bufA, t);                       // tail chunk 24
}

extern "C" void kernel_launch(void* const* d_in, const int* in_sizes, int n_in,
                              void* d_out, int out_size, void* d_ws, size_t ws_size,
                              hipStream_t stream) {
    const float* u = (const float*)d_in[0];           // (B,N,T)
    const float* theta_base = (const float*)d_in[1];  // (1,N,1)
    float* out = (float*)d_out;
    float* spikes = out;                               // first output
    float* vhist = out + (size_t)B_ * N_ * T_;         // second output

    const int total = B_ * N_;        // 32768 threads = 512 waves
    const int block = 64;
    const int grid = total / block;   // 512 blocks -> 2 per CU
    lif_kernel<<<grid, block, 0, stream>>>(u, theta_base, spikes, vhist);
}

// Round 3
// 133.715 us; speedup vs baseline: 1.8975x; 1.2991x over previous
//
#include <hip/hip_runtime.h>

// LIF neuron bank: B=16, N=2048, T=1000. Sequential scan in T per neuron.
//
// R2: producer-consumer wave specialization. 512 blocks x 192 threads:
//   wave 0: compute (64 neurons). Double-buffered register u-loads (its vmcnt
//           queue holds ONLY loads -> no store-drain on the critical path).
//           Writes s/v per step into LDS tiles transposed [t][neuron]
//           (lane = neuron -> conflict-free ds_write_b32).
//   wave 1: streams spikes chunks LDS -> global (float4, back-to-back).
//   wave 2: streams vhist  chunks LDS -> global.
// Double-buffered LDS, one __syncthreads per chunk: compute writes par=c&1
// while storers read par=(c-1)&1 -- always disjoint.
//
// FP discipline: reference does NOT contract mul+add into FMA; use
// __fmul_rn/__fadd_rn/__fsub_rn to stay bit-exact (R0/R1: absmax 0.0).

constexpr int B_ = 16;
constexpr int N_ = 2048;
constexpr int T_ = 1000;
constexpr int CHUNK = 40;            // steps per chunk
constexpr int NV4 = CHUNK / 4;       // 10 float4 per chunk
constexpr int NCHUNK = T_ / CHUNK;   // 25 chunks
constexpr int NPAIR = NCHUNK / 2;    // 12 pairs + 1 tail chunk

__global__ __launch_bounds__(192) void lif_kernel(
    const float* __restrict__ u,          // (B, N, T)
    const float* __restrict__ theta_base, // (1, N, 1) -> N floats
    float* __restrict__ spikes,           // (B, N, T)
    float* __restrict__ vhist)            // (B, N, T)
{
    __shared__ float s_lds[2][CHUNK][64];   // [par][t][neuron]
    __shared__ float v_lds[2][CHUNK][64];

    const int lane = threadIdx.x & 63;
    const int wid = threadIdx.x >> 6;
    const int neuron = blockIdx.x * 64 + lane;   // 512*64 = 32768 = B*N
    const size_t row = (size_t)neuron * T_;

    if (wid == 0) {
        // ---------------- compute wave ----------------
        const float tb = theta_base[neuron & (N_ - 1)];
        const float c5 = __fmul_rn(tb, 0.005f);   // tb * (1-0.995) rounded
        float v = 0.0f, theta = tb, ref = 0.0f;
        const float* up = u + row;

        float4 bufA[NV4], bufB[NV4];   // named bufs: static indexing only

        auto load_chunk = [&](float4 (&buf)[NV4], int t0) {
#pragma unroll
            for (int i = 0; i < NV4; ++i)
                buf[i] = *reinterpret_cast<const float4*>(up + t0 + 4 * i);
        };

        auto process = [&](const float4 (&buf)[NV4], int par) {
#pragma unroll
            for (int i = 0; i < NV4; ++i) {
                const float uin[4] = {buf[i].x, buf[i].y, buf[i].z, buf[i].w};
#pragma unroll
                for (int k = 0; k < 4; ++k) {
                    // u_eff = u_t * (1 - (ref>0))
                    const float ueff = (ref > 0.0f) ? 0.0f : uin[k];
                    // v = 0.95*v + u_eff   (separate mul/add, no FMA)
                    v = __fadd_rn(__fmul_rn(0.95f, v), ueff);
                    // s = (v - theta >= 0)
                    const float d = __fsub_rn(v, theta);
                    const bool s = (d >= 0.0f);
                    // v -= s*theta
                    v = s ? __fsub_rn(v, theta) : v;
                    // ref = max(ref-1,0); if (s) ref = 2
                    ref = fmaxf(__fsub_rn(ref, 1.0f), 0.0f);
                    ref = s ? 2.0f : ref;
                    // theta = theta*0.995 + tb*0.005 + 0.35*s
                    theta = __fadd_rn(__fmul_rn(theta, 0.995f), c5);
                    theta = s ? __fadd_rn(theta, 0.35f) : theta;

                    s_lds[par][4 * i + k][lane] = s ? 1.0f : 0.0f;
                    v_lds[par][4 * i + k][lane] = v;
                }
            }
        };

        load_chunk(bufA, 0);
        int t = 0;
#pragma unroll 1
        for (int c = 0; c < NPAIR; ++c) {
            load_chunk(bufB, t + CHUNK);   // chunk 2c+1
            process(bufA, 0);              // chunk 2c   -> par 0
            __syncthreads();
            t += CHUNK;
            load_chunk(bufA, t + CHUNK);   // chunk 2c+2 (<=24, always valid)
            process(bufB, 1);              // chunk 2c+1 -> par 1
            __syncthreads();
            t += CHUNK;
        }
        process(bufA, 0);                  // chunk 24 -> par 0
        __syncthreads();                   // barrier #25
    } else {
        // ---------------- storer waves ----------------
        float* gout = (wid == 1) ? spikes : vhist;
        const float (*src)[CHUNK][64] = (wid == 1) ? s_lds : v_lds;
        float* gp = gout + row;

#pragma unroll 1
        for (int c = 0; c < NCHUNK; ++c) {
            if (c > 0) {
                const int par = (c - 1) & 1;
                const int t0 = (c - 1) * CHUNK;
#pragma unroll
                for (int i = 0; i < NV4; ++i) {
                    float4 w;
                    w.x = src[par][4 * i + 0][lane];
                    w.y = src[par][4 * i + 1][lane];
                    w.z = src[par][4 * i + 2][lane];
                    w.w = src[par][4 * i + 3][lane];
                    *reinterpret_cast<float4*>(gp + t0 + 4 * i) = w;
                }
            }
            __syncthreads();
        }
        // tail: chunk 24 lives in par 0; compute's barrier #25 already passed
        {
            const int t0 = (NCHUNK - 1) * CHUNK;
#pragma unroll
            for (int i = 0; i < NV4; ++i) {
                float4 w;
                w.x = src[0][4 * i + 0][lane];
                w.y = src[0][4 * i + 1][lane];
                w.z = src[0][4 * i + 2][lane];
                w.w = src[0][4 * i + 3][lane];
                *reinterpret_cast<float4*>(gp + t0 + 4 * i) = w;
            }
        }
    }
}

extern "C" void kernel_launch(void* const* d_in, const int* in_sizes, int n_in,
                              void* d_out, int out_size, void* d_ws, size_t ws_size,
                              hipStream_t stream) {
    const float* u = (const float*)d_in[0];           // (B,N,T)
    const float* theta_base = (const float*)d_in[1];  // (1,N,1)
    float* out = (float*)d_out;
    float* spikes = out;                               // first output
    float* vhist = out + (size_t)B_ * N_ * T_;         // second output

    const int grid = (B_ * N_) / 64;   // 512 blocks (64 neurons each)
    lif_kernel<<<grid, 192, 0, stream>>>(u, theta_base, spikes, vhist);
}